// Round 11
// baseline (166.137 us; speedup 1.0000x reference)
//
#include <hip/hip_runtime.h>

#define HID 512
#define SEQ 4096
#define NB 32
#define BS 64          // s-rows per chunk
#define NSB 8          // s-blocks per batch row (256 blocks = 1/CU)
#define CPB 8          // chunks per block (NSB*CPB*BS = SEQ)
#define CH 514         // [m, den, num[512]]

typedef __attribute__((ext_vector_type(8))) __bf16 bf16x8;
typedef __attribute__((ext_vector_type(4))) __bf16 bf16x4;
typedef __attribute__((ext_vector_type(16))) float f32x16;
typedef __attribute__((ext_vector_type(4))) float f32x4;

__device__ __forceinline__ float tanh_fast(float v) {
    float e = __expf(2.f * v);
    return 1.f - __fdividef(2.f, e + 1.f);
}

// ---- Kernel 1: build W1_a in MFMA-fragment order (h-tile ht, k-slice ks):
//      w1af[((ht*32+ks)*64 + lane)*8 + j] = bf16(W1a[k=ks*16+(lane>>5)*8+j][h=ht*32+(lane&31)])
__global__ void build_w1af(const float* __restrict__ W1,
                           unsigned short* __restrict__ w1af) {
    __shared__ float tile[64][65];
    int t = threadIdx.x;
    int lane = t & 63;
    int r4 = t >> 6;            // 0..3
    int k0 = blockIdx.x * 64;
    int h0 = blockIdx.y * 64;
#pragma unroll
    for (int i = 0; i < 16; ++i) {
        int r = i * 4 + r4;     // k-row within tile
        tile[r][lane] = W1[(size_t)(HID + k0 + r) * HID + h0 + lane];
    }
    __syncthreads();
#pragma unroll
    for (int i = 0; i < 16; ++i) {
        int hr = i * 4 + r4;    // h-row
        int h = h0 + hr, k = k0 + lane;
        __bf16 bv = (__bf16)tile[lane][hr];
        int ht = h >> 5, hl = h & 31;
        int ks = k >> 4, g = (k >> 3) & 1, j = k & 7;
        size_t off = (((size_t)ht * 32 + ks) * 64 + g * 32 + hl) * 8 + j;
        w1af[off] = *(unsigned short*)&bv;
    }
}

// ---- Kernel 2: pre_part[b][kc][h] = sum_{k in kc-chunk} prev[b][k]*W1_h[k][h] ----
__global__ void pre_partial(const float* __restrict__ prev,
                            const float* __restrict__ W1,
                            float* __restrict__ pre_part) {
    __shared__ float pl[128];
    int kc = blockIdx.x;   // 0..3
    int b  = blockIdx.y;
    int t  = threadIdx.x;
    if (t < 128) pl[t] = prev[b * HID + kc * 128 + t];
    __syncthreads();
    int h0 = 2 * t;
    float ax = 0.f, ay = 0.f;
    for (int k = 0; k < 128; ++k) {
        float pv = pl[k];
        float2 wv = *(const float2*)(W1 + (size_t)(kc * 128 + k) * HID + h0);
        ax += pv * wv.x;
        ay += pv * wv.y;
    }
    float* dst = pre_part + ((size_t)b * 4 + kc) * HID + h0;
    dst[0] = ax; dst[1] = ay;
}

// ---- Kernel 3: T14 double-buffered fused kernel.  grid (8 sb, 32 b) x 512.
//      8 waves; wave owns 2 h-tiles (64 h) x 2 s-tiles: acc = 64 AGPR only.
//      Per chunk: [issue 16 NT loads for c+1] -> K-loop(c) -> tail(c) ->
//      cvt+ds_write(c+1 into other 64 KiB buffer) -> bar.  HBM latency and
//      transfer of c+1 hide under K-loop+tail of c.  ~190 regs: fits 256. ----
__global__ __launch_bounds__(512, 2)
void score_ctx(const float* __restrict__ ann,
               const unsigned short* __restrict__ w1af,
               const float* __restrict__ pre_part,
               const float* __restrict__ b1,
               const float* __restrict__ W2,
               float* __restrict__ cout) {
    __shared__ unsigned short bufA[BS * 512];   // 64 KiB, XOR-swizzled bf16
    __shared__ unsigned short bufB[BS * 512];   // 64 KiB
    __shared__ float pre_lds[512];
    __shared__ float w2_lds[512];
    __shared__ float red[8][64];

    const int sb = blockIdx.x, b = blockIdx.y;
    const int t = threadIdx.x;
    const int wv = t >> 6;        // 0..7, wave owns h in [wv*64, wv*64+64)
    const int lane = t & 63;
    const int sl = lane & 31;
    const int g = lane >> 5;

    {
        float pp = b1[t];
#pragma unroll
        for (int kc = 0; kc < 4; ++kc)
            pp += pre_part[((size_t)b * 4 + kc) * HID + t];
        pre_lds[t] = pp;
        w2_lds[t] = W2[t];
    }

    const float* abase0 = ann + ((size_t)b * SEQ + (size_t)sb * (CPB * BS)) * 512;

    // staging: chunk = 64 rows x 512 fp32 = 8192 f32x4; thread does 16.
    // idx = t + i*512; row = idx>>7; c4 = idx&127.
    f32x4 sf[16];   // 64 VGPRs in flight, statically indexed

    // ---- prologue: stage chunk 0 into bufA (synchronous) ----
    {
        const float* ab = abase0;
#pragma unroll
        for (int i = 0; i < 16; ++i)
            sf[i] = __builtin_nontemporal_load((const f32x4*)(ab) + t + i * 512);
#pragma unroll
        for (int i = 0; i < 16; ++i) {
            int idx = t + i * 512;
            int row = idx >> 7, c4 = idx & 127;
            bf16x4 pk;
            pk[0] = (__bf16)sf[i][0]; pk[1] = (__bf16)sf[i][1];
            pk[2] = (__bf16)sf[i][2]; pk[3] = (__bf16)sf[i][3];
            unsigned boff = ((unsigned)(row * 1024 + c4 * 8)) ^ ((unsigned)(row & 7) << 4);
            *(bf16x4*)((char*)bufA + boff) = pk;
        }
    }
    __syncthreads();

    float m_run = -3.0e38f, d_run = 0.f, ctx = 0.f;

    const unsigned short* wb0 = w1af + (size_t)(2 * wv) * 16384 + (size_t)lane * 8;
    const unsigned short* wb1 = wb0 + 16384;
    const unsigned swz = (unsigned)(sl & 7) << 4;     // (32+sl)&7 == sl&7
    const unsigned rb0 = (unsigned)(( 0 + sl) * 1024 + g * 16);
    const unsigned rb1 = (unsigned)((32 + sl) * 1024 + g * 16);

#pragma unroll 1
    for (int c = 0; c < CPB; ++c) {
        unsigned short* cur = (c & 1) ? bufB : bufA;
        unsigned short* nxt = (c & 1) ? bufA : bufB;

        // ---- issue-early: 16 NT loads for chunk c+1 (used only at write-late;
        //      in-order vmcnt retire means K-loop A-load waits absorb latency) ----
        if (c < CPB - 1) {
            const float* ab = abase0 + (size_t)(c + 1) * BS * 512;
#pragma unroll
            for (int i = 0; i < 16; ++i)
                sf[i] = __builtin_nontemporal_load((const f32x4*)(ab) + t + i * 512);
        }

        // ---- K-loop: 2 h-tiles x 2 s-tiles, 4 MFMA per ks ----
        f32x16 c00, c01, c10, c11;
#pragma unroll
        for (int r = 0; r < 16; ++r) { c00[r] = 0.f; c01[r] = 0.f; c10[r] = 0.f; c11[r] = 0.f; }
#pragma unroll 2
        for (int ks = 0; ks < 32; ++ks) {
            bf16x8 A0 = *(const bf16x8*)(wb0 + ks * 512);
            bf16x8 A1 = *(const bf16x8*)(wb1 + ks * 512);
            unsigned kb = (unsigned)ks * 32u;
            bf16x8 B0 = *(const bf16x8*)((const char*)cur + ((rb0 + kb) ^ swz));
            bf16x8 B1 = *(const bf16x8*)((const char*)cur + ((rb1 + kb) ^ swz));
            c00 = __builtin_amdgcn_mfma_f32_32x32x16_bf16(A0, B0, c00, 0, 0, 0);
            c01 = __builtin_amdgcn_mfma_f32_32x32x16_bf16(A0, B1, c01, 0, 0, 0);
            c10 = __builtin_amdgcn_mfma_f32_32x32x16_bf16(A1, B0, c10, 0, 0, 0);
            c11 = __builtin_amdgcn_mfma_f32_32x32x16_bf16(A1, B1, c11, 0, 0, 0);
        }

        // ---- epilogue: tanh + w2-dot over this wave's 64 h's, per s-tile ----
        float sp0 = 0.f, sp1 = 0.f;
#pragma unroll
        for (int r = 0; r < 16; ++r) {
            int hl = (r & 3) + 8 * (r >> 2) + 4 * g;
            int ha = wv * 64 + hl, hb = ha + 32;
            float pa = pre_lds[ha], wa = w2_lds[ha];
            float pb = pre_lds[hb], wb = w2_lds[hb];
            sp0 += wa * tanh_fast(c00[r] + pa) + wb * tanh_fast(c10[r] + pb);
            sp1 += wa * tanh_fast(c01[r] + pa) + wb * tanh_fast(c11[r] + pb);
        }
        sp0 += __shfl_xor(sp0, 32);
        sp1 += __shfl_xor(sp1, 32);
        if (lane < 32) { red[wv][sl] = sp0; red[wv][32 + sl] = sp1; }
        __syncthreads();

        // ---- softmax: all waves redundantly (score for s = lane) ----
        float sc = 0.f;
#pragma unroll
        for (int q = 0; q < 8; ++q) sc += red[q][lane];
        float m = sc;
#pragma unroll
        for (int off = 32; off; off >>= 1) m = fmaxf(m, __shfl_xor(m, off));
        float p = __expf(sc - m);
        float d = p;
#pragma unroll
        for (int off = 32; off; off >>= 1) d += __shfl_xor(d, off);

        float m_new = fmaxf(m_run, m);
        float so = __expf(m_run - m_new), s_c = __expf(m - m_new);
        d_run = d_run * so + d * s_c;

        // ---- ctx numerator: thread t owns col t; p broadcast via shfl ----
        float na = 0.f;
#pragma unroll 16
        for (int s = 0; s < BS; ++s) {
            float ps = __shfl(p, s);
            unsigned boff = ((unsigned)(s * 1024 + 2 * t)) ^ ((unsigned)(s & 7) << 4);
            unsigned short us = *(const unsigned short*)((const char*)cur + boff);
            na += ps * __uint_as_float((unsigned)us << 16);
        }
        ctx = ctx * so + na * s_c;
        m_run = m_new;

        // ---- write-late: cvt + drain into the other buffer ----
        if (c < CPB - 1) {
#pragma unroll
            for (int i = 0; i < 16; ++i) {
                int idx = t + i * 512;
                int row = idx >> 7, c4 = idx & 127;
                bf16x4 pk;
                pk[0] = (__bf16)sf[i][0]; pk[1] = (__bf16)sf[i][1];
                pk[2] = (__bf16)sf[i][2]; pk[3] = (__bf16)sf[i][3];
                unsigned boff = ((unsigned)(row * 1024 + c4 * 8)) ^ ((unsigned)(row & 7) << 4);
                *(bf16x4*)((char*)nxt + boff) = pk;
            }
        }
        __syncthreads();
    }

    float* cb = cout + ((size_t)b * NSB + sb) * CH;
    cb[2 + t] = ctx;
    if (t == 0) { cb[0] = m_run; cb[1] = d_run; }
}

// ---- Kernel 4: merge 8 s-block partials per batch row ----
__global__ void finalize_ctx(const float* __restrict__ cout,
                             float* __restrict__ out) {
    int b = blockIdx.x, t = threadIdx.x;   // 512 threads
    float ms[NSB];
    float M = -3.0e38f;
#pragma unroll
    for (int s = 0; s < NSB; ++s) {
        ms[s] = cout[((size_t)b * NSB + s) * CH];
        M = fmaxf(M, ms[s]);
    }
    float D = 0.f, val = 0.f;
#pragma unroll
    for (int s = 0; s < NSB; ++s) {
        const float* cb = cout + ((size_t)b * NSB + s) * CH;
        float e = __expf(ms[s] - M);
        D += e * cb[1];
        val += e * cb[2 + t];
    }
    out[(size_t)b * 512 + t] = val / D;
}

extern "C" void kernel_launch(void* const* d_in, const int* in_sizes, int n_in,
                              void* d_out, int out_size, void* d_ws, size_t ws_size,
                              hipStream_t stream) {
    (void)in_sizes; (void)n_in; (void)out_size; (void)ws_size;
    const float* prev = (const float*)d_in[0];
    const float* ann  = (const float*)d_in[1];
    const float* W1   = (const float*)d_in[2];
    const float* b1   = (const float*)d_in[3];
    const float* W2   = (const float*)d_in[4];
    // b2 (d_in[5]) cancels in softmax; unused.
    float* out = (float*)d_out;

    char* ws = (char*)d_ws;
    unsigned short* w1af = (unsigned short*)ws;               // 512*512*2 = 524288 B
    float* pre_part = (float*)(ws + 524288);                  // 32*4*512*4 = 262144 B
    float* cout     = (float*)(ws + 524288 + 262144);         // 32*8*514*4 = 526336 B

    build_w1af<<<dim3(8, 8), dim3(256), 0, stream>>>(W1, w1af);
    pre_partial<<<dim3(4, NB), dim3(256), 0, stream>>>(prev, W1, pre_part);
    score_ctx<<<dim3(NSB, NB), dim3(512), 0, stream>>>(ann, w1af, pre_part, b1, W2, cout);
    finalize_ctx<<<dim3(NB), dim3(512), 0, stream>>>(cout, out);
}